// Round 3
// baseline (517.311 us; speedup 1.0000x reference)
//
#include <hip/hip_runtime.h>
#include <hip/hip_bf16.h>
#include <stdint.h>

// TubeletEmbedding: video [64,16,1,84,84] f32 -> tubelets [73728,98] -> GEMM
// with W [1024,98] -> out [64,1152,1024] f32 + bias + pos_embed.
// Output-write-bound (~336 MB total HBM). bf16 MFMA (tol 0.135, measured 0.031).
//
// R3: fused single-dispatch. im2col gathers video straight into LDS (no A_ws
// round-trip). MFMA operands SWAPPED (W rows = C rows = embed dim) so each
// lane's f32x4 accumulator = 4 consecutive e -> dwordx4 stores/pos/bias.
// nt = bid&7: the 8 N-tiles of one M-tile run concurrently on the 8 XCDs
// (video fetched from HBM once, 7 L3 hits; W-slice L2-resident per XCD).

typedef __bf16 bf16_t;
typedef bf16_t bf16x8 __attribute__((ext_vector_type(8)));
typedef float f32x4 __attribute__((ext_vector_type(4)));

#define B_      64
#define N_TOK   1152
#define M_TOT   (B_ * N_TOK)   // 73728
#define E_      1024
#define KP      128            // padded K (real K = 98)
#define K_REAL  98
#define BM      128
#define BN      128
#define MT_N    (M_TOT / BM)   // 576
#define NT_N    (E_ / BN)      // 8

// ---- pass 1: W f32 [1024][98] -> bf16 [1024][128], zero-pad, swizzled ----
__global__ void wconv_kernel(const float* __restrict__ W, bf16_t* __restrict__ Wb) {
    int idx = blockIdx.x * 256 + threadIdx.x;   // covers 1024*128
    int k = idx & (KP - 1);
    int e = idx >> 7;
    float v = (k < K_REAL) ? W[e * K_REAL + k] : 0.f;
    Wb[e * KP + (k ^ ((e & 7) << 3))] = (bf16_t)v;
}

// ---- pass 2: fused im2col + GEMM ----
__global__ __launch_bounds__(256) void gemm_kernel(
    const float* __restrict__ video, const bf16_t* __restrict__ Wb,
    const float* __restrict__ bias, const float* __restrict__ pos,
    float* __restrict__ out) {
    __shared__ __align__(16) bf16_t As[BM * KP];   // tokens  32 KB
    __shared__ __align__(16) bf16_t Bs[BN * KP];   // W rows  32 KB

    const int tid  = threadIdx.x;
    const int wv   = tid >> 6;
    const int lane = tid & 63;

    const int bid = blockIdx.x;
    const int nt  = bid & 7;          // consecutive bids -> different XCDs
    const int mt  = bid >> 3;
    const long m0 = (long)mt * BM;
    const int  n0 = nt * BN;
    const int  bb = mt / 9;           // batch (1152 = 9 tiles of 128)
    const int  ntok_blk = (mt - bb * 9) * BM;

    // Stage W-slice: contiguous 32 KB, pre-swizzled in global.
    {
        const char* gB = (const char*)(Wb + (long)n0 * KP);
        char* lB = (char*)Bs;
#pragma unroll
        for (int i = 0; i < 8; ++i) {
            int off = (wv * 8 + i) * 1024;
            __builtin_amdgcn_global_load_lds(
                (const __attribute__((address_space(1))) void*)(gB + off + lane * 16),
                (__attribute__((address_space(3))) void*)(lB + off), 16, 0, 0);
        }
    }

    // Gather-stage A: 128 tokens x 16 granules of 8 bf16. 8 granules/thread.
    {
        const float* vbase = video + (size_t)(bb * 16) * 7056;
#pragma unroll
        for (int it = 0; it < 8; ++it) {
            int gi    = it * 256 + tid;
            int m_loc = gi >> 4;
            int g     = gi & 15;
            int n  = ntok_blk + m_loc;
            int d  = n / 144, s = n - d * 144;
            int i  = s / 12,  jj = s - i * 12;
            const float* fbase = vbase + (size_t)(d * 2) * 7056 + (i * 7) * 84 + jj * 7;
            bf16_t vals[8];
#pragma unroll
            for (int u = 0; u < 8; ++u) {
                int k = g * 8 + u;
                float v = 0.f;
                if (k < K_REAL) {
                    int ts = (k >= 49) ? 1 : 0;
                    int f  = k - ts * 49;
                    int fy = f / 7, fx = f - fy * 7;
                    v = fbase[ts * 7056 + fy * 84 + fx];
                }
                vals[u] = (bf16_t)v;
            }
            int col = (g * 8) ^ ((m_loc & 7) << 3);
            *(bf16x8*)&As[m_loc * KP + col] = *(const bf16x8*)vals;
        }
    }
    __syncthreads();   // drains vmcnt (gload_lds) + lgkmcnt (ds_write)

    const int we = wv >> 1, wt = wv & 1;   // 2x2 waves: 64e x 64tok each
    const int lr = lane & 15;
    const int lk = (lane >> 4) * 8;
    const int xsw = (lr & 7) << 3;

    f32x4 acc[4][4];                       // [ei][ti]
#pragma unroll
    for (int ei = 0; ei < 4; ++ei)
#pragma unroll
        for (int ti = 0; ti < 4; ++ti)
            acc[ei][ti] = (f32x4){0.f, 0.f, 0.f, 0.f};

#pragma unroll
    for (int kk = 0; kk < 4; ++kk) {
        bf16x8 a[4], b[4];
        const int col = (kk * 32 + lk) ^ xsw;
#pragma unroll
        for (int ei = 0; ei < 4; ++ei)
            a[ei] = *(const bf16x8*)&Bs[(we * 64 + ei * 16 + lr) * KP + col];  // W rows (e)
#pragma unroll
        for (int ti = 0; ti < 4; ++ti)
            b[ti] = *(const bf16x8*)&As[(wt * 64 + ti * 16 + lr) * KP + col];  // tokens
#pragma unroll
        for (int ei = 0; ei < 4; ++ei)
#pragma unroll
            for (int ti = 0; ti < 4; ++ti)
                acc[ei][ti] = __builtin_amdgcn_mfma_f32_16x16x32_bf16(
                    a[ei], b[ti], acc[ei][ti], 0, 0, 0);
    }

    // Epilogue. C/D layout: col(lane&15) = token, row((lane>>4)*4+reg) = e.
    // Each lane's f32x4 = 4 consecutive e -> dwordx4 everywhere.
    const int row4 = (lane >> 4) * 4;
#pragma unroll
    for (int ei = 0; ei < 4; ++ei) {
        const int e_base = n0 + we * 64 + ei * 16 + row4;
        const f32x4 bias4 = *(const f32x4*)&bias[e_base];
#pragma unroll
        for (int ti = 0; ti < 4; ++ti) {
            const int tok = wt * 64 + ti * 16 + lr;
            const f32x4 pos4 = *(const f32x4*)&pos[(ntok_blk + tok) * E_ + e_base];
            f32x4 vout = acc[ei][ti] + bias4 + pos4;
            __builtin_nontemporal_store(
                vout, (f32x4*)&out[(m0 + tok) * (long)E_ + e_base]);
        }
    }
}

extern "C" void kernel_launch(void* const* d_in, const int* in_sizes, int n_in,
                              void* d_out, int out_size, void* d_ws, size_t ws_size,
                              hipStream_t stream) {
    const float* video = (const float*)d_in[0];  // 64*16*1*84*84
    const float* W     = (const float*)d_in[1];  // 1024*98
    const float* bias  = (const float*)d_in[2];  // 1024
    const float* pos   = (const float*)d_in[3];  // 1*1152*1024
    float* out = (float*)d_out;

    bf16_t* W_ws = (bf16_t*)d_ws;                // 1024*128*2 = 256 KB

    wconv_kernel<<<(E_ * KP) / 256, 256, 0, stream>>>(W, W_ws);
    gemm_kernel<<<MT_N * NT_N, 256, 0, stream>>>(video, W_ws, bias, pos, out);
}

// Round 4
// 498.692 us; speedup vs baseline: 1.0373x; 1.0373x over previous
//
#include <hip/hip_runtime.h>
#include <hip/hip_bf16.h>
#include <stdint.h>

// TubeletEmbedding: video [64,16,1,84,84] f32 -> tubelets [73728,98] -> GEMM
// with W [1024,98] -> out [64,1152,1024] f32 + bias + pos_embed.
//
// R4: barrier-free streaming kernel. No LDS, no __syncthreads, no A_ws.
//  - Swapped MFMA operands: A = W rows (e), B = tokens. The im2col granule
//    (8 consecutive k of one token) IS the per-lane B-fragment -> gather
//    video straight into registers.
//  - W fragments (16 x bf16x8 per wave) register-resident across all chunks.
//  - acc lane layout: 4 consecutive e -> dwordx4 NT stores + dwordx4 pos/bias.
//  - nt = bid&7 pins e-slice to an XCD (pos/W slices L2-resident);
//    consecutive-chunk m-walk keeps video L2-local (HBM once via L3).
// Kernel-side floor ~ (302 out + 28 video + 5 pos) MB / 6.3 TB/s ~ 53 us.
// (dur_us additionally carries ~237 us of harness poison fills.)

typedef __bf16 bf16_t;
typedef bf16_t bf16x8 __attribute__((ext_vector_type(8)));
typedef float f32x4 __attribute__((ext_vector_type(4)));

#define E_      1024
#define KP      128
#define K_REAL  98
#define N_TOK   1152
#define M_TOT   73728
#define CHUNK   128          // tokens per block-chunk
#define NCHUNK  (M_TOT / CHUNK)   // 576
#define CPB     8            // chunks per block
#define MG_N    (NCHUNK / CPB)    // 72
#define GRID    (MG_N * 8)        // 576 blocks

// ---- pass 1: W f32 [1024][98] -> bf16 [1024][128] zero-padded (no swizzle) ----
__global__ void wconv_kernel(const float* __restrict__ W, bf16_t* __restrict__ Wb) {
    int idx = blockIdx.x * 256 + threadIdx.x;   // 1024*128
    int k = idx & (KP - 1);
    int e = idx >> 7;
    Wb[idx] = (bf16_t)((k < K_REAL) ? W[e * K_REAL + k] : 0.f);
}

// ---- pass 2: streaming fused im2col + GEMM, no LDS / no barriers ----
__global__ __launch_bounds__(256, 2) void embed_kernel(
    const float* __restrict__ video, const bf16_t* __restrict__ Wb,
    const float* __restrict__ bias, const float* __restrict__ pos,
    float* __restrict__ out) {
    const int tid  = threadIdx.x;
    const int wv   = tid >> 6;
    const int lane = tid & 63;
    const int we   = wv >> 1, wt = wv & 1;   // wave: 64e x 64tok
    const int lr   = lane & 15;              // A-row(e) / B-col(token)
    const int hi   = lane >> 4;
    const int lk   = hi * 8;                 // k-offset within fragment

    const int bid = blockIdx.x;
    const int nt  = bid & 7;                 // e-slice -> XCD
    const int mg  = bid >> 3;
    const int n0  = nt * 128 + we * 64;      // wave e-base

    // W fragments, register-resident: e = n0 + ei*16 + lr, k = kk*32 + lk + u
    bf16x8 wfrag[4][4];
#pragma unroll
    for (int ei = 0; ei < 4; ++ei)
#pragma unroll
        for (int kk = 0; kk < 4; ++kk)
            wfrag[ei][kk] = *(const bf16x8*)&Wb[(n0 + ei * 16 + lr) * KP + kk * 32 + lk];

    f32x4 bias4[4];
#pragma unroll
    for (int ei = 0; ei < 4; ++ei)
        bias4[ei] = *(const f32x4*)&bias[n0 + ei * 16 + hi * 4];

#pragma unroll 1
    for (int j = 0; j < CPB; ++j) {
        const int m0 = (mg * CPB + j) * CHUNK + wt * 64;   // wave token base

        // Gather B-fragments: token m = m0 + ti*16 + lr, k = kk*32 + lk + u
        // m -> video[b, 2d+ts, iy*7+fy, jx*7+fx], k = ts*49 + fy*7 + fx
        bf16x8 bfrag[4][4];
#pragma unroll
        for (int ti = 0; ti < 4; ++ti) {
            const int m = m0 + ti * 16 + lr;
            const int b = m / N_TOK;
            const int n = m - b * N_TOK;
            const int d = n / 144, s = n - d * 144;
            const int iy = s / 12, jx = s - iy * 12;
            const float* fb = video + (size_t)(b * 16 + d * 2) * 7056
                              + iy * 7 * 84 + jx * 7;
#pragma unroll
            for (int kk = 0; kk < 3; ++kk) {       // k <= 95 < 98: no predicate
                bf16_t tmp[8];
#pragma unroll
                for (int u = 0; u < 8; ++u) {
                    int k  = kk * 32 + lk + u;
                    int ts = (k >= 49) ? 1 : 0;
                    int f  = k - ts * 49;
                    int fy = f / 7, fx = f - fy * 7;
                    tmp[u] = (bf16_t)fb[ts * 7056 + fy * 84 + fx];
                }
                bfrag[ti][kk] = *(const bf16x8*)tmp;
            }
            {   // kk = 3: only k = 96,97 real (lanes hi==0, u<2)
                bf16_t tmp[8] = {bf16_t(0.f), bf16_t(0.f), bf16_t(0.f), bf16_t(0.f),
                                 bf16_t(0.f), bf16_t(0.f), bf16_t(0.f), bf16_t(0.f)};
                if (hi == 0) {
                    tmp[0] = (bf16_t)fb[7565];   // ts=1, fy=6, fx=5  (k=96)
                    tmp[1] = (bf16_t)fb[7566];   // ts=1, fy=6, fx=6  (k=97)
                }
                bfrag[ti][3] = *(const bf16x8*)tmp;
            }
        }

        // MFMA: acc[ei][ti], C row = e (lane>>4)*4+reg, col = token lane&15
        f32x4 acc[4][4];
#pragma unroll
        for (int ei = 0; ei < 4; ++ei)
#pragma unroll
            for (int ti = 0; ti < 4; ++ti)
                acc[ei][ti] = (f32x4){0.f, 0.f, 0.f, 0.f};
#pragma unroll
        for (int kk = 0; kk < 4; ++kk)
#pragma unroll
            for (int ei = 0; ei < 4; ++ei)
#pragma unroll
                for (int ti = 0; ti < 4; ++ti)
                    acc[ei][ti] = __builtin_amdgcn_mfma_f32_16x16x32_bf16(
                        wfrag[ei][kk], bfrag[ti][kk], acc[ei][ti], 0, 0, 0);

        // Epilogue: dwordx4 everywhere (4 consecutive e per lane)
#pragma unroll
        for (int ti = 0; ti < 4; ++ti) {
            const int m    = m0 + ti * 16 + lr;
            const int ntok = m % N_TOK;
#pragma unroll
            for (int ei = 0; ei < 4; ++ei) {
                const int e_base = n0 + ei * 16 + hi * 4;
                const f32x4 pos4 = *(const f32x4*)&pos[(size_t)ntok * E_ + e_base];
                f32x4 vout = acc[ei][ti] + bias4[ei] + pos4;
                __builtin_nontemporal_store(
                    vout, (f32x4*)&out[(size_t)m * E_ + e_base]);
            }
        }
    }
}

extern "C" void kernel_launch(void* const* d_in, const int* in_sizes, int n_in,
                              void* d_out, int out_size, void* d_ws, size_t ws_size,
                              hipStream_t stream) {
    const float* video = (const float*)d_in[0];  // 64*16*1*84*84
    const float* W     = (const float*)d_in[1];  // 1024*98
    const float* bias  = (const float*)d_in[2];  // 1024
    const float* pos   = (const float*)d_in[3];  // 1*1152*1024
    float* out = (float*)d_out;

    bf16_t* W_ws = (bf16_t*)d_ws;                // 1024*128*2 = 256 KB

    wconv_kernel<<<(E_ * KP) / 256, 256, 0, stream>>>(W, W_ws);
    embed_kernel<<<GRID, 256, 0, stream>>>(video, W_ws, bias, pos, out);
}